// Round 1
// baseline (734.709 us; speedup 1.0000x reference)
//
#include <hip/hip_runtime.h>
#include <hip/hip_bf16.h>

#define H 128
#define H1 129
#define NSLAB (H1 * H1)          // 16641 slabs of 129 W1-rows each
#define KP 164                   // LDS k-pitch (bf16 elems)
#define NBLK 768                 // 3 blocks / CU (exact residency at launch_bounds(256,3))
#define NREP 8                   // replicated accumulators to cut atomic contention

typedef __attribute__((ext_vector_type(8))) short short8;
typedef __attribute__((ext_vector_type(4))) float float4v;
typedef __attribute__((ext_vector_type(2))) int int2v;
typedef __attribute__((ext_vector_type(4))) int int4v;

__device__ __forceinline__ unsigned short f2bf_bits(float x) {
    return __builtin_bit_cast(unsigned short, __float2bfloat16(x));
}
__device__ __forceinline__ unsigned packbf(float x, float y) {
    return (unsigned)f2bf_bits(x) | ((unsigned)f2bf_bits(y) << 16);
}

// Stage 1: y1_raw[b,h] = sum_{ij,k} a_h[b,i] v_h[b,j] t_h[b,k] W1[ij*129+k, h]
// Per slab ij: D = t_h @ W1slab via MFMA, then y1acc += av * D.
// Pipelined: slab n+1's global loads (W + a/v scalars) are in flight in VGPRs
// across the MFMA phase and both barriers of slab n (reg-staged prefetch).
__global__ __launch_bounds__(256, 3) void k1_partial(
        const float* __restrict__ v, const float* __restrict__ a,
        const float* __restrict__ t, const float* __restrict__ W1,
        float* __restrict__ acc)
{
    __shared__ short lds[64 * KP];   // transposed slab: [h][k] bf16

    const int tid  = threadIdx.x;
    const int wv   = tid >> 6;       // wave 0..3 -> owns batch rows [16wv,16wv+16)
    const int lane = tid & 63;
    const int quad = lane >> 4;
    const int l15  = lane & 15;

    // zero-fill pad region k in [130, KP) once (staging writes only k<130)
    for (int idx = tid; idx < 64 * (KP - 130); idx += 256) {
        int n = idx / (KP - 130), k = 130 + idx % (KP - 130);
        lds[n * KP + k] = 0;
    }

    // t_h fragments (A operand), bf16, zero-padded for k>=129.
    short8 tf[5];
    const int bt = 16 * wv + l15;
    #pragma unroll
    for (int s = 0; s < 5; ++s) {
        #pragma unroll
        for (int j = 0; j < 8; ++j) {
            int k = 32 * s + 8 * quad + j;
            float val = (k == 0) ? 1.0f : ((k <= H) ? t[bt * H + k - 1] : 0.0f);
            tf[s][j] = (short)f2bf_bits(val);
        }
    }

    const float4v vz = {0.f, 0.f, 0.f, 0.f};
    float4v y1acc[4] = {vz, vz, vz, vz};

    const int s0 = (int)(((long long)blockIdx.x * NSLAB) / NBLK);
    const int s1 = (int)(((long long)(blockIdx.x + 1) * NSLAB) / NBLK);

    const int q = tid & 15;          // staging: column group (coalesced)
    const int p16 = tid >> 4;        // staging: row-pair group
    const int br0 = 16 * wv + quad * 4;  // C/D batch-row base for this thread

    float4v ra[4], rb[4];            // prefetch registers (W slab)
    float lastrow;
    float ahc[4], vhc[4], ahn[4], vhn[4];

    const float* Wb = W1 + (long long)s0 * (H1 * 64);

    auto ISSUE = [&](const float* Wp) {
        #pragma unroll
        for (int it = 0; it < 4; ++it) {
            int p = it * 16 + p16;
            ra[it] = *reinterpret_cast<const float4v*>(Wp + (2 * p) * 64 + q * 4);
            rb[it] = *reinterpret_cast<const float4v*>(Wp + (2 * p + 1) * 64 + q * 4);
        }
        lastrow = (tid < 64) ? Wp[128 * 64 + tid] : 0.f;
    };

    auto WRITE = [&]() {             // convert fp32->bf16, transpose into LDS
        #pragma unroll
        for (int it = 0; it < 4; ++it) {
            int p = it * 16 + p16;
            #pragma unroll
            for (int c = 0; c < 4; ++c) {
                int n = q * 4 + c;
                *reinterpret_cast<unsigned*>(&lds[n * KP + 2 * p]) = packbf(ra[it][c], rb[it][c]);
            }
        }
        if (tid < 64)
            *reinterpret_cast<unsigned*>(&lds[tid * KP + 128]) = packbf(lastrow, 0.f);
    };

    auto LOADAV = [&](int si, int sj, float* ah, float* vh) {
        #pragma unroll
        for (int r = 0; r < 4; ++r) {
            int br = br0 + r;
            ah[r] = (si == 0) ? 1.0f : a[br * H + si - 1];
            vh[r] = (sj == 0) ? 1.0f : v[br * H + sj - 1];
        }
    };

    auto MFMA_ACC = [&]() {          // consume LDS slab, accumulate with av scale
        float4v D[4] = {vz, vz, vz, vz};
        #pragma unroll
        for (int s = 0; s < 5; ++s) {
            #pragma unroll
            for (int nt = 0; nt < 4; ++nt) {
                int n = nt * 16 + l15;
                int sa = n * KP + 32 * s + 8 * quad;
                int2v lo = *reinterpret_cast<const int2v*>(&lds[sa]);
                int2v hi = *reinterpret_cast<const int2v*>(&lds[sa + 4]);
                int4v w; w.x = lo.x; w.y = lo.y; w.z = hi.x; w.w = hi.y;
                short8 bf = __builtin_bit_cast(short8, w);
                D[nt] = __builtin_amdgcn_mfma_f32_16x16x32_bf16(tf[s], bf, D[nt], 0, 0, 0);
            }
        }
        float4v avv;
        #pragma unroll
        for (int r = 0; r < 4; ++r) avv[r] = ahc[r] * vhc[r];
        #pragma unroll
        for (int nt = 0; nt < 4; ++nt) y1acc[nt] += avv * D[nt];
    };

    // ---- prologue: stage slab s0, prefetch slab s0+1 ----
    int si = s0 / H1, sj = s0 % H1;
    ISSUE(Wb);
    LOADAV(si, sj, ahc, vhc);
    WRITE();                          // only exposed load latency in the kernel
    Wb += H1 * 64;
    int si_n = si, sj_n = sj + 1; if (sj_n == H1) { sj_n = 0; ++si_n; }
    if (s0 + 1 < s1) { ISSUE(Wb); LOADAV(si_n, sj_n, ahn, vhn); }
    __syncthreads();

    // ---- main loop: MFMA slab sl-1 while slab sl's loads are in flight ----
    for (int sl = s0 + 1; sl < s1; ++sl) {
        MFMA_ACC();                   // slab sl-1
        #pragma unroll
        for (int r = 0; r < 4; ++r) { ahc[r] = ahn[r]; vhc[r] = vhn[r]; }
        __syncthreads();              // all waves done reading LDS
        WRITE();                      // slab sl (vmcnt covered by MFMA phase)
        Wb += H1 * 64;
        ++sj_n; if (sj_n == H1) { sj_n = 0; ++si_n; }
        if (sl + 1 < s1) { ISSUE(Wb); LOADAV(si_n, sj_n, ahn, vhn); }
        __syncthreads();
    }
    MFMA_ACC();                       // last slab

    // ---- reduce across blocks (8-way replicated to cut contention) ----
    const int rep = blockIdx.x & (NREP - 1);
    float* accr = acc + rep * (64 * 64);
    #pragma unroll
    for (int nt = 0; nt < 4; ++nt) {
        int h = nt * 16 + l15;
        #pragma unroll
        for (int r = 0; r < 4; ++r)
            unsafeAtomicAdd(&accr[(br0 + r) * 64 + h], y1acc[nt][r]);
    }
}

// Stage 2: sum replicas, bias+relu, layer2, layer3 (tiny: 64x64 -> 64x32 -> 64)
__global__ void k2_tail(const float* __restrict__ acc, const float* __restrict__ b1,
                        const float* __restrict__ W2, const float* __restrict__ b2,
                        const float* __restrict__ W3, const float* __restrict__ b3,
                        float* __restrict__ out)
{
    __shared__ float y1s[64 * 64];
    __shared__ float y2s[64 * 32];
    const int tid = threadIdx.x;

    for (int e = tid; e < 64 * 64; e += 256) {
        float x = b1[e & 63];
        #pragma unroll
        for (int r = 0; r < NREP; ++r) x += acc[r * 64 * 64 + e];
        y1s[e] = x > 0.f ? x : 0.f;
    }
    __syncthreads();
    for (int e = tid; e < 64 * 32; e += 256) {
        int b = e >> 5, h2 = e & 31;
        float s = b2[h2];
        #pragma unroll 8
        for (int h = 0; h < 64; ++h) s += y1s[b * 64 + h] * W2[h * 32 + h2];
        y2s[e] = s > 0.f ? s : 0.f;
    }
    __syncthreads();
    if (tid < 64) {
        float s = b3[0];
        #pragma unroll
        for (int h2 = 0; h2 < 32; ++h2) s += y2s[tid * 32 + h2] * W3[h2];
        out[tid] = s;
    }
}

extern "C" void kernel_launch(void* const* d_in, const int* in_sizes, int n_in,
                              void* d_out, int out_size, void* d_ws, size_t ws_size,
                              hipStream_t stream) {
    const float* v  = (const float*)d_in[0];
    const float* a  = (const float*)d_in[1];
    const float* t  = (const float*)d_in[2];
    const float* W1 = (const float*)d_in[3];
    const float* b1 = (const float*)d_in[4];
    const float* W2 = (const float*)d_in[5];
    const float* b2 = (const float*)d_in[6];
    const float* W3 = (const float*)d_in[7];
    const float* b3 = (const float*)d_in[8];
    float* acc = (float*)d_ws;

    hipMemsetAsync(acc, 0, NREP * 64 * 64 * sizeof(float), stream);
    hipLaunchKernelGGL(k1_partial, dim3(NBLK), dim3(256), 0, stream, v, a, t, W1, acc);
    hipLaunchKernelGGL(k2_tail, dim3(1), dim3(256), 0, stream,
                       acc, b1, W2, b2, W3, b3, (float*)d_out);
}

// Round 2
// 728.109 us; speedup vs baseline: 1.0091x; 1.0091x over previous
//
#include <hip/hip_runtime.h>
#include <hip/hip_bf16.h>

#define H 128
#define H1 129
#define NSLAB (H1 * H1)          // 16641 slabs of 129 W1-rows each
#define KP 164                   // LDS k-pitch (bf16 elems)
#define NBLK 768                 // 3 blocks / CU (exact residency at launch_bounds(256,3))
#define NREP 8                   // replicated accumulators to cut atomic contention

typedef __attribute__((ext_vector_type(8))) short short8;
typedef __attribute__((ext_vector_type(4))) float float4v;
typedef __attribute__((ext_vector_type(2))) int int2v;
typedef __attribute__((ext_vector_type(4))) int int4v;

__device__ __forceinline__ unsigned short f2bf_bits(float x) {
    return __builtin_bit_cast(unsigned short, __float2bfloat16(x));
}
__device__ __forceinline__ unsigned packbf(float x, float y) {
    return (unsigned)f2bf_bits(x) | ((unsigned)f2bf_bits(y) << 16);
}

// Raw barrier WITHOUT the vmcnt(0) drain that __syncthreads' workgroup fence
// forces. LDS visibility needs lgkmcnt(0) only; global loads in flight to
// VGPRs must NOT be drained here (that was killing the prefetch pipeline).
#define BAR_LGKM() do {                                           \
    asm volatile("s_waitcnt lgkmcnt(0)" ::: "memory");            \
    __builtin_amdgcn_s_barrier();                                 \
    asm volatile("" ::: "memory");                                \
} while (0)

// Stage 1: y1_raw[b,h] = sum_{ij,k} a_h[b,i] v_h[b,j] t_h[b,k] W1[ij*129+k, h]
// Per slab ij: D = t_h @ W1slab via MFMA, then y1acc += av * D.
// Pipelined: slab n+1's global loads (W + a/v scalars) stay in flight in VGPRs
// across the MFMA phase and BOTH raw barriers of slab n.
__global__ __launch_bounds__(256, 3) void k1_partial(
        const float* __restrict__ v, const float* __restrict__ a,
        const float* __restrict__ t, const float* __restrict__ W1,
        float* __restrict__ acc)
{
    __shared__ short lds[64 * KP];   // transposed slab: [h][k] bf16

    const int tid  = threadIdx.x;
    const int wv   = tid >> 6;       // wave 0..3 -> owns batch rows [16wv,16wv+16)
    const int lane = tid & 63;
    const int quad = lane >> 4;
    const int l15  = lane & 15;

    // zero-fill pad region k in [130, KP) once (staging writes only k<130)
    for (int idx = tid; idx < 64 * (KP - 130); idx += 256) {
        int n = idx / (KP - 130), k = 130 + idx % (KP - 130);
        lds[n * KP + k] = 0;
    }

    // t_h fragments (A operand), bf16, zero-padded for k>=129.
    short8 tf[5];
    const int bt = 16 * wv + l15;
    #pragma unroll
    for (int s = 0; s < 5; ++s) {
        #pragma unroll
        for (int j = 0; j < 8; ++j) {
            int k = 32 * s + 8 * quad + j;
            float val = (k == 0) ? 1.0f : ((k <= H) ? t[bt * H + k - 1] : 0.0f);
            tf[s][j] = (short)f2bf_bits(val);
        }
    }

    const float4v vz = {0.f, 0.f, 0.f, 0.f};
    float4v y1acc[4] = {vz, vz, vz, vz};

    const int s0 = (int)(((long long)blockIdx.x * NSLAB) / NBLK);
    const int s1 = (int)(((long long)(blockIdx.x + 1) * NSLAB) / NBLK);

    const int q = tid & 15;          // staging: column group (coalesced)
    const int p16 = tid >> 4;        // staging: row-pair group
    const int br0 = 16 * wv + quad * 4;  // C/D batch-row base for this thread

    float4v ra[4], rb[4];            // prefetch registers (W slab)
    float lastrow;
    float ahc[4], vhc[4], ahn[4], vhn[4];

    auto ISSUE = [&](const float* Wp) {
        #pragma unroll
        for (int it = 0; it < 4; ++it) {
            int p = it * 16 + p16;
            ra[it] = *reinterpret_cast<const float4v*>(Wp + (2 * p) * 64 + q * 4);
            rb[it] = *reinterpret_cast<const float4v*>(Wp + (2 * p + 1) * 64 + q * 4);
        }
        lastrow = (tid < 64) ? Wp[128 * 64 + tid] : 0.f;
    };

    auto WRITE = [&]() {             // convert fp32->bf16, transpose into LDS
        #pragma unroll
        for (int it = 0; it < 4; ++it) {
            int p = it * 16 + p16;
            #pragma unroll
            for (int c = 0; c < 4; ++c) {
                int n = q * 4 + c;
                *reinterpret_cast<unsigned*>(&lds[n * KP + 2 * p]) = packbf(ra[it][c], rb[it][c]);
            }
        }
        if (tid < 64)
            *reinterpret_cast<unsigned*>(&lds[tid * KP + 128]) = packbf(lastrow, 0.f);
    };

    auto LOADAV = [&](int si, int sj, float* ah, float* vh) {
        #pragma unroll
        for (int r = 0; r < 4; ++r) {
            int br = br0 + r;
            ah[r] = (si == 0) ? 1.0f : a[br * H + si - 1];
            vh[r] = (sj == 0) ? 1.0f : v[br * H + sj - 1];
        }
    };

    auto MFMA_ACC = [&]() {          // consume LDS slab, accumulate with av scale
        float4v D[4] = {vz, vz, vz, vz};
        #pragma unroll
        for (int s = 0; s < 5; ++s) {
            #pragma unroll
            for (int nt = 0; nt < 4; ++nt) {
                int n = nt * 16 + l15;
                int sa = n * KP + 32 * s + 8 * quad;
                int2v lo = *reinterpret_cast<const int2v*>(&lds[sa]);
                int2v hi = *reinterpret_cast<const int2v*>(&lds[sa + 4]);
                int4v w; w.x = lo.x; w.y = lo.y; w.z = hi.x; w.w = hi.y;
                short8 bf = __builtin_bit_cast(short8, w);
                D[nt] = __builtin_amdgcn_mfma_f32_16x16x32_bf16(tf[s], bf, D[nt], 0, 0, 0);
            }
        }
        float4v avv;
        #pragma unroll
        for (int r = 0; r < 4; ++r) avv[r] = ahc[r] * vhc[r];
        #pragma unroll
        for (int nt = 0; nt < 4; ++nt) y1acc[nt] += avv * D[nt];
    };

    // ---- prologue: issue slab s0's loads ----
    int si = s0 / H1, sj = s0 % H1;
    const float* Wb = W1 + (long long)s0 * (H1 * 64);
    ISSUE(Wb);
    LOADAV(si, sj, ahc, vhc);
    int si_n = si, sj_n = sj;

    // ---- main loop ----
    for (int sl = s0; sl < s1; ++sl) {
        WRITE();                      // waits (compiler-inserted vmcnt) on ra/rb only
        if (sl + 1 < s1) {
            Wb += H1 * 64;
            ++sj_n; if (sj_n == H1) { sj_n = 0; ++si_n; }
            ISSUE(Wb);                // in flight across barriers + MFMA phase
            LOADAV(si_n, sj_n, ahn, vhn);
        }
        BAR_LGKM();                   // slab visible to all waves (no vmcnt drain)
        MFMA_ACC();                   // slab sl
        #pragma unroll
        for (int r = 0; r < 4; ++r) { ahc[r] = ahn[r]; vhc[r] = vhn[r]; }
        BAR_LGKM();                   // all waves done reading before next WRITE
    }

    // ---- reduce across blocks (8-way replicated to cut contention) ----
    const int rep = blockIdx.x & (NREP - 1);
    float* accr = acc + rep * (64 * 64);
    #pragma unroll
    for (int nt = 0; nt < 4; ++nt) {
        int h = nt * 16 + l15;
        #pragma unroll
        for (int r = 0; r < 4; ++r)
            unsafeAtomicAdd(&accr[(br0 + r) * 64 + h], y1acc[nt][r]);
    }
}

// Stage 2: sum replicas, bias+relu, layer2, layer3 (tiny: 64x64 -> 64x32 -> 64)
__global__ void k2_tail(const float* __restrict__ acc, const float* __restrict__ b1,
                        const float* __restrict__ W2, const float* __restrict__ b2,
                        const float* __restrict__ W3, const float* __restrict__ b3,
                        float* __restrict__ out)
{
    __shared__ float y1s[64 * 64];
    __shared__ float y2s[64 * 32];
    const int tid = threadIdx.x;

    for (int e = tid; e < 64 * 64; e += 256) {
        float x = b1[e & 63];
        #pragma unroll
        for (int r = 0; r < NREP; ++r) x += acc[r * 64 * 64 + e];
        y1s[e] = x > 0.f ? x : 0.f;
    }
    __syncthreads();
    for (int e = tid; e < 64 * 32; e += 256) {
        int b = e >> 5, h2 = e & 31;
        float s = b2[h2];
        #pragma unroll 8
        for (int h = 0; h < 64; ++h) s += y1s[b * 64 + h] * W2[h * 32 + h2];
        y2s[e] = s > 0.f ? s : 0.f;
    }
    __syncthreads();
    if (tid < 64) {
        float s = b3[0];
        #pragma unroll
        for (int h2 = 0; h2 < 32; ++h2) s += y2s[tid * 32 + h2] * W3[h2];
        out[tid] = s;
    }
}

extern "C" void kernel_launch(void* const* d_in, const int* in_sizes, int n_in,
                              void* d_out, int out_size, void* d_ws, size_t ws_size,
                              hipStream_t stream) {
    const float* v  = (const float*)d_in[0];
    const float* a  = (const float*)d_in[1];
    const float* t  = (const float*)d_in[2];
    const float* W1 = (const float*)d_in[3];
    const float* b1 = (const float*)d_in[4];
    const float* W2 = (const float*)d_in[5];
    const float* b2 = (const float*)d_in[6];
    const float* W3 = (const float*)d_in[7];
    const float* b3 = (const float*)d_in[8];
    float* acc = (float*)d_ws;

    hipMemsetAsync(acc, 0, NREP * 64 * 64 * sizeof(float), stream);
    hipLaunchKernelGGL(k1_partial, dim3(NBLK), dim3(256), 0, stream, v, a, t, W1, acc);
    hipLaunchKernelGGL(k2_tail, dim3(1), dim3(256), 0, stream,
                       acc, b1, W2, b2, W3, b3, (float*)d_out);
}